// Round 9
// baseline (86.378 us; speedup 1.0000x reference)
//
#include <hip/hip_runtime.h>
#include <stdint.h>

// Problem constants (B=2, H=8, N=2048, D=64, f32 in/out).
#define B_ 2
#define H_ 8
#define N_ 2048
#define D_ 64
#define BH_ (B_ * H_)
#define NROWS (BH_ * N_)      // 32768
#define TPB_ 544              // tasks per bh: sum_{g2=0}^{63} ceil((2g2+2)/8)
#define TASKS (TPB_ * BH_)    // 8704 = 8 * 1088
#define MAXCH 16              // max chunks per 32-row group
#define EPSF 8e-3f            // margin below which we re-resolve the row in f64
#define INFF __int_as_float(0x7f800000)

using u64 = unsigned long long;
using u32 = unsigned int;
typedef __attribute__((ext_vector_type(8))) short short8;   // 8 bf16
typedef __attribute__((ext_vector_type(4))) float f32x4;

#define MFMA16(A, B, C) __builtin_amdgcn_mfma_f32_16x16x32_bf16((A), (B), (C), 0, 0, 0)

// ---------------------------------------------------------------------------
// Prep (verbatim from rounds 7/8, passed): split k into bf16 hi/lo in MFMA
// B-FRAGMENT layout [jg][h(2)][lane(64)][16B] so phase1 reads one fragment as
// a single coalesced 1KB global_load_dwordx4. Writer thread (row r, group kg):
// h = kg>>2, lane = (kg&3)*16 + (r&15). Also ksq[r].
// ---------------------------------------------------------------------------
__global__ __launch_bounds__(256) void prep_k(
    const float* __restrict__ k, char* __restrict__ khi_g,
    char* __restrict__ klo_g, float* __restrict__ ksq_g)
{
  const int t = (int)blockIdx.x * 256 + threadIdx.x;  // NROWS*8 total
  const int r = t >> 3, kg = t & 7;
  const float* kp = k + (size_t)r * D_ + kg * 8;
  const float4 f0 = *(const float4*)kp;
  const float4 f1 = *(const float4*)(kp + 4);
  const float vv[8] = {f0.x, f0.y, f0.z, f0.w, f1.x, f1.y, f1.z, f1.w};
  u32 hw[4], lw[4];
  float ps = 0.f;
  #pragma unroll
  for (int e = 0; e < 4; ++e) {
    const float va = vv[2 * e], vb = vv[2 * e + 1];
    ps = fmaf(va, va, ps); ps = fmaf(vb, vb, ps);
    const u32 ha = __float_as_uint(va) & 0xFFFF0000u;
    const u32 hb = __float_as_uint(vb) & 0xFFFF0000u;
    hw[e] = (ha >> 16) | hb;
    const u32 la = __float_as_uint(va - __uint_as_float(ha));
    const u32 lb = __float_as_uint(vb - __uint_as_float(hb));
    lw[e] = (la >> 16) | (lb & 0xFFFF0000u);
  }
  const size_t off = ((size_t)(r >> 4) * 2 + (kg >> 2)) * 1024 +
                     (size_t)(((kg & 3) << 4) + (r & 15)) * 16;
  *(uint4*)(khi_g + off) = make_uint4(hw[0], hw[1], hw[2], hw[3]);
  *(uint4*)(klo_g + off) = make_uint4(lw[0], lw[1], lw[2], lw[3]);
  float ssum = ps;                                    // |k_row|^2
  ssum += __shfl_xor(ssum, 1);
  ssum += __shfl_xor(ssum, 2);
  ssum += __shfl_xor(ssum, 4);
  if (kg == 0) ksq_g[r] = ssum;
}

__device__ __forceinline__ void cvt_hilo(const float* p, short8& hi, short8& lo) {
  const float4 f0 = *(const float4*)p;
  const float4 f1 = *(const float4*)(p + 4);
  const float vv[8] = {f0.x, f0.y, f0.z, f0.w, f1.x, f1.y, f1.z, f1.w};
  #pragma unroll
  for (int e = 0; e < 8; ++e) {
    const float v = vv[e];
    const u32 hb = __float_as_uint(v) & 0xFFFF0000u;
    hi[e] = (short)(hb >> 16);
    lo[e] = (short)(__float_as_uint(v - __uint_as_float(hb)) >> 16);
  }
}

// ---------------------------------------------------------------------------
// Phase 1: UNIFORM 1-wave tasks. Task = (bh, 32-row group g2, chunk of <=8
// j-subtiles). Block = 64 threads = 1 wave (perfect balance, no intra-block
// coupling); 8704 tasks = 8.5 waves/SIMD queue depth; launch_bounds(64,4)
// caps VGPR at 128 (budget ~115 -> fragments stay register-resident).
// Per subtile: 4 coalesced 1KB B-fragment loads (register-prefetched one
// subtile ahead) + 12 MFMA (2 s-sets x {hi*hi,hi*lo,lo*hi} x 2 K-halves) +
// float best/sec/argmin tracking of score = ksq_j - 2 q.k (qsq constant per
// row: cancels in argmin and in the EPSF margin). Ascending j per lane +
// strict < keeps first index; sortable-key u64 cross-lane reduce over the 16
// col-slots (u64-min == first-index tie-break, matching np.argmax).
// XCD swizzle: each XCD owns a contiguous 1088-task range (~2 bh, 1MB frag
// working set, L2-resident).
// ---------------------------------------------------------------------------
__global__ __launch_bounds__(64, 4) void phase1(
    const float* __restrict__ q, const char* __restrict__ khi_g,
    const char* __restrict__ klo_g, const float* __restrict__ ksq_g,
    u64* __restrict__ bestc, u32* __restrict__ secc)
{
  const int b = (int)blockIdx.x;
  const int task = (b & 7) * (TASKS / 8) + (b >> 3);  // XCD swizzle (bijective)
  const int bh = task / TPB_;
  const int rem = task - bh * TPB_;
  int a = 0;                                          // quad index: cum = 2a(a+1)
  while (2 * (a + 1) * (a + 2) <= rem) ++a;           // a in 0..15
  const int idx = rem - 2 * a * (a + 1);
  const int g2 = 4 * a + idx / (a + 1);
  const int c = idx - (idx / (a + 1)) * (a + 1);
  const int jfirst = c * 8;
  const int jlast = min(jfirst + 7, 2 * g2 + 1);      // inclusive subtile idx

  const int lane = threadIdx.x & 63;
  const int grp = lane >> 4, c0 = lane & 15;
  const int i0 = g2 * 32;

  // ---- q: 2 named A-frag sets (rows i0 + {0,16} + c0), bf16 hi/lo ----
  short8 ah00, ah01, al00, al01, ah10, ah11, al10, al11;
  {
    const float* q0 = q + ((size_t)bh * N_ + i0 + c0) * D_ + grp * 8;
    cvt_hilo(q0, ah00, al00);
    cvt_hilo(q0 + 32, ah01, al01);
    const float* q1 = q0 + 16 * D_;
    cvt_hilo(q1, ah10, al10);
    cvt_hilo(q1 + 32, ah11, al11);
  }

  // ---- running best/sec over the chunk ----
  float bf[2][4], sf[2][4];
  u32 bj[2][4];
  #pragma unroll
  for (int s = 0; s < 2; ++s)
    #pragma unroll
    for (int r2 = 0; r2 < 4; ++r2) {
      bf[s][r2] = INFF; sf[s][r2] = INFF; bj[s][r2] = 0;
    }

  const size_t fb = (size_t)bh * 128 * 2048;          // 256KB per bh
  const char* ph = khi_g + fb + (size_t)jfirst * 2048 + lane * 16;
  const char* pl = klo_g + fb + (size_t)jfirst * 2048 + lane * 16;
  const float* pk = ksq_g + (size_t)bh * N_ + jfirst * 16 + c0;

  short8 ch0 = *(const short8*)(ph);
  short8 ch1 = *(const short8*)(ph + 1024);
  short8 cl0 = *(const short8*)(pl);
  short8 cl1 = *(const short8*)(pl + 1024);
  float cks = *pk;

  for (int js = jfirst; js <= jlast; ++js) {
    // prefetch next subtile (redundant re-load of current on last iter)
    const int adv = (js < jlast) ? 1 : 0;
    const short8 nh0 = *(const short8*)(ph + adv * 2048);
    const short8 nh1 = *(const short8*)(ph + adv * 2048 + 1024);
    const short8 nl0 = *(const short8*)(pl + adv * 2048);
    const short8 nl1 = *(const short8*)(pl + adv * 2048 + 1024);
    const float nks = pk[adv * 16];
    ph += adv * 2048; pl += adv * 2048; pk += adv * 16;

    const int jcol = js * 16 + c0;
    // ---- s = 0 (rows i0..i0+15); skip subtiles above its diagonal ----
    if (js <= 2 * g2) {
      const bool dsub = (js == 2 * g2);
      f32x4 aA = {0.f, 0.f, 0.f, 0.f}, aB = {0.f, 0.f, 0.f, 0.f};
      aA = MFMA16(ah00, ch0, aA);  aB = MFMA16(ah01, ch1, aB);
      aA = MFMA16(ah00, cl0, aA);  aB = MFMA16(ah01, cl1, aB);
      aA = MFMA16(al00, ch0, aA);  aB = MFMA16(al01, ch1, aB);
      #pragma unroll
      for (int reg = 0; reg < 4; ++reg) {
        float score = fmaf(-2.f, aA[reg] + aB[reg], cks);
        if (dsub && jcol > i0 + grp * 4 + reg) score = INFF;
        const float loser = fmaxf(bf[0][reg], score);
        sf[0][reg] = fminf(sf[0][reg], loser);
        if (score < bf[0][reg]) bj[0][reg] = (u32)jcol;
        bf[0][reg] = fminf(bf[0][reg], score);
      }
    }
    // ---- s = 1 (rows i0+16..i0+31); jlast <= 2g2+1 so always active ----
    {
      const bool dsub = (js == 2 * g2 + 1);
      f32x4 aA = {0.f, 0.f, 0.f, 0.f}, aB = {0.f, 0.f, 0.f, 0.f};
      aA = MFMA16(ah10, ch0, aA);  aB = MFMA16(ah11, ch1, aB);
      aA = MFMA16(ah10, cl0, aA);  aB = MFMA16(ah11, cl1, aB);
      aA = MFMA16(al10, ch0, aA);  aB = MFMA16(al11, ch1, aB);
      #pragma unroll
      for (int reg = 0; reg < 4; ++reg) {
        float score = fmaf(-2.f, aA[reg] + aB[reg], cks);
        if (dsub && jcol > i0 + 16 + grp * 4 + reg) score = INFF;
        const float loser = fmaxf(bf[1][reg], score);
        sf[1][reg] = fminf(sf[1][reg], loser);
        if (score < bf[1][reg]) bj[1][reg] = (u32)jcol;
        bf[1][reg] = fminf(bf[1][reg], score);
      }
    }
    ch0 = nh0; ch1 = nh1; cl0 = nl0; cl1 = nl1; cks = nks;
  }

  // ---- cross-lane reduce over the 16 col-slots; store one entry/row ----
  #pragma unroll
  for (int s = 0; s < 2; ++s) {
    #pragma unroll
    for (int reg = 0; reg < 4; ++reg) {
      const u32 bbits = __float_as_uint(bf[s][reg]);
      const u32 key = bbits ^ (u32)(((int)bbits >> 31) | 0x80000000);
      u64 pkk = ((u64)key << 32) | bj[s][reg];
      float sv = sf[s][reg];
      #pragma unroll
      for (int m = 1; m < 16; m <<= 1) {
        const u64 opk = (u64)__shfl_xor((long long)pkk, m);
        const float osv = __shfl_xor(sv, m);
        const u32 mk = (u32)(pkk >> 32), ok = (u32)(opk >> 32);
        const u32 lk = (opk < pkk) ? mk : ok;         // loser's key
        const u32 lb = (lk & 0x80000000u) ? (lk ^ 0x80000000u) : ~lk;
        sv = fminf(fminf(sv, osv), __uint_as_float(lb));
        if (opk < pkk) pkk = opk;
      }
      if (c0 == 0) {
        const size_t rr = (size_t)bh * N_ + i0 + s * 16 + grp * 4 + reg;
        bestc[(size_t)c * NROWS + rr] = pkk;
        secc[(size_t)c * NROWS + rr] = __float_as_uint(sv);
      }
    }
  }
}

// ---------------------------------------------------------------------------
// Combine + f64 fix + gather, fused. Block = 256 thr handles 64 rows:
// stage A (t<64) reduces the row's <=16 chunk partials (u64-min keeps first
// index; best value decoded from sortable key), flags near-ties into LDS;
// stage B: for each flagged row (rare), the whole block re-resolves it in f64
// (ascending-j first-on-tie, identical numerics to prior exact_gather);
// stage C: all 256 threads gather v rows to out (float4).
// ---------------------------------------------------------------------------
__global__ __launch_bounds__(256) void combine_fix_gather(
    const u64* __restrict__ bestc, const u32* __restrict__ secc,
    const float* __restrict__ q, const float* __restrict__ k,
    const float* __restrict__ v, float* __restrict__ out)
{
  __shared__ u32 idx_s[64];
  __shared__ u32 flg_s[64];
  __shared__ double qd[D_];
  __shared__ double sd[256];
  __shared__ int sj[256];
  const int tid = threadIdx.x;
  const int r0 = (int)blockIdx.x * 64;

  if (tid < 64) {
    const int r = r0 + tid;
    const int i = r & (N_ - 1);
    const int nch = (2 * (i >> 5) + 9) >> 3;   // chunks covering this group
    u64 b0 = ~0ull;
    float bcur = INFF, s1 = INFF;
    int cstar = 0;
    for (int c2 = 0; c2 < nch; ++c2) {
      const u64 kk = bestc[(size_t)c2 * NROWS + r];
      const u32 key = (u32)(kk >> 32);
      const u32 bits = (key & 0x80000000u) ? (key ^ 0x80000000u) : ~key;
      const float f = __uint_as_float(bits);
      if (kk < b0) { s1 = fminf(s1, bcur); b0 = kk; bcur = f; cstar = c2; }
      else s1 = fminf(s1, f);
    }
    s1 = fminf(s1, __uint_as_float(secc[(size_t)cstar * NROWS + r]));
    idx_s[tid] = (u32)(b0 & 0xFFFFu);
    flg_s[tid] = ((s1 - bcur) < EPSF) ? 1u : 0u;   // NaN-safe: INF-INF -> 0
  }
  __syncthreads();

  // ---- rare: exact f64 re-resolution of flagged rows (block-cooperative) ----
  for (int rl = 0; rl < 64; ++rl) {
    if (!flg_s[rl]) continue;                    // block-uniform branch
    const int r = r0 + rl;
    const int bh = r >> 11;
    const int i = r & (N_ - 1);
    const float* qr = q + (size_t)r * D_;
    const float* kb = k + (size_t)bh * N_ * D_;
    if (tid < D_) qd[tid] = (double)qr[tid];
    __syncthreads();
    double qsqd = 0.0;
    for (int d = 0; d < D_; ++d) qsqd = fma(qd[d], qd[d], qsqd);
    double bbest = 1e300;
    int bjj = 0;
    for (int j = tid; j <= i; j += 256) {
      const float* kr = kb + (size_t)j * D_;
      double a0 = 0, a1 = 0, s0 = 0, s1d = 0;
      for (int d = 0; d < D_; d += 2) {
        const double k0 = (double)kr[d], k1 = (double)kr[d + 1];
        a0 = fma(qd[d], k0, a0);  a1 = fma(qd[d + 1], k1, a1);
        s0 = fma(k0, k0, s0);     s1d = fma(k1, k1, s1d);
      }
      const double raw = (qsqd + (s0 + s1d)) - 2.0 * (a0 + a1);
      const double d2 = raw > 0.0 ? raw : 0.0;
      if (d2 < bbest) { bbest = d2; bjj = j; }   // ascending j -> first on tie
    }
    sd[tid] = bbest; sj[tid] = bjj;
    __syncthreads();
    for (int s = 128; s > 0; s >>= 1) {
      if (tid < s) {
        const double ob = sd[tid + s]; const int oj = sj[tid + s];
        if (ob < sd[tid] || (ob == sd[tid] && oj < sj[tid])) {
          sd[tid] = ob; sj[tid] = oj;
        }
      }
      __syncthreads();
    }
    if (tid == 0) idx_s[rl] = (u32)sj[0];
    __syncthreads();
  }

  // ---- gather: out[r,:] = v[bh, idx[r], :] ----
  #pragma unroll
  for (int iter = 0; iter < 4; ++iter) {
    const int tk = tid + iter * 256;
    const int rl = tk >> 4, cc = tk & 15;
    const int r = r0 + rl;
    const u32 j = idx_s[rl];
    const int bh = r >> 11;
    const float4 val = ((const float4*)(v + ((size_t)bh * N_ + j) * D_))[cc];
    ((float4*)(out + (size_t)r * D_))[cc] = val;
  }
}

// ---------------------------------------------------------------------------
extern "C" void kernel_launch(void* const* d_in, const int* in_sizes, int n_in,
                              void* d_out, int out_size, void* d_ws,
                              size_t ws_size, hipStream_t stream) {
  const float* q = (const float*)d_in[0];
  const float* k = (const float*)d_in[1];
  const float* v = (const float*)d_in[2];
  float* out = (float*)d_out;

  // ws layout (256 MiB available):
  // [256K: ksq 128K][1M: khi 4M][8M: klo 4M][16M: bestc 4M][24M: secc 2M]
  char* ws = (char*)d_ws;
  float* ksq_g = (float*)(ws + 256 * 1024);
  char* khi_g = ws + 1ull * 1024 * 1024;
  char* klo_g = ws + 8ull * 1024 * 1024;
  u64* bestc = (u64*)(ws + 16ull * 1024 * 1024);
  u32* secc = (u32*)(ws + 24ull * 1024 * 1024);

  prep_k<<<(NROWS * 8) / 256, 256, 0, stream>>>(k, khi_g, klo_g, ksq_g);
  phase1<<<TASKS, 64, 0, stream>>>(q, khi_g, klo_g, ksq_g, bestc, secc);
  combine_fix_gather<<<NROWS / 64, 256, 0, stream>>>(bestc, secc, q, k, v, out);
}